// Round 1
// baseline (643.643 us; speedup 1.0000x reference)
//
#include <hip/hip_runtime.h>
#include <math.h>

#define EMBED 1024
#define HDIM  64
#define BATCH 16
#define SEQ   2048
#define MTOT  (BATCH*SEQ)   // 32768

// ---------------------------------------------------------------------------
// Kernel 1: fused QKV projection (fp32 tiled GEMM)
//   out[MTOT,64] = X[MTOT,1024] @ W[1024,64] + b   (blockIdx.y picks q/k/v)
//   BM=256, BN=64, BK=16; 256 threads; 8x8 per-thread tile.
// ---------------------------------------------------------------------------
__global__ __launch_bounds__(256)
void qkv_proj_kernel(const float* __restrict__ X,
                     const float* __restrict__ Wq, const float* __restrict__ bq,
                     const float* __restrict__ Wk, const float* __restrict__ bk,
                     const float* __restrict__ Wv, const float* __restrict__ bv,
                     float* __restrict__ Q, float* __restrict__ K, float* __restrict__ V)
{
    const float* W; const float* bias; float* out;
    if (blockIdx.y == 0)      { W = Wq; bias = bq; out = Q; }
    else if (blockIdx.y == 1) { W = Wk; bias = bk; out = K; }
    else                      { W = Wv; bias = bv; out = V; }

    __shared__ float Xs[16][256];   // transposed: Xs[k][m]
    __shared__ float Ws[16][64];    // Ws[k][n]

    const int tid = threadIdx.x;
    const int tx  = tid & 7;        // 8 col-groups of 8
    const int ty  = tid >> 3;       // 32 row-groups of 8
    const int m0  = blockIdx.x * 256;

    const int lf4  = tid & 3;       // which float4 within the 16-wide K slice
    const int lrow = tid >> 2;      // 0..63
    const int wk   = tid >> 4;      // 0..15
    const int wc4  = tid & 15;      // 0..15

    float acc[8][8];
    #pragma unroll
    for (int r = 0; r < 8; ++r)
        #pragma unroll
        for (int c = 0; c < 8; ++c) acc[r][c] = 0.f;

    for (int k0 = 0; k0 < EMBED; k0 += 16) {
        // X tile (256 rows x 16 k), stored transposed
        #pragma unroll
        for (int h = 0; h < 4; ++h) {
            const int row = lrow + 64*h;
            const float4 xv = *(const float4*)(X + (size_t)(m0 + row)*EMBED + k0 + 4*lf4);
            Xs[4*lf4+0][row] = xv.x;
            Xs[4*lf4+1][row] = xv.y;
            Xs[4*lf4+2][row] = xv.z;
            Xs[4*lf4+3][row] = xv.w;
        }
        // W tile (16 k x 64 n)
        {
            const float4 wv = *(const float4*)(W + (size_t)(k0 + wk)*HDIM + 4*wc4);
            *(float4*)&Ws[wk][4*wc4] = wv;
        }
        __syncthreads();

        #pragma unroll
        for (int kk = 0; kk < 16; ++kk) {
            float a_[8], b_[8];
            *(float4*)&a_[0] = *(const float4*)&Xs[kk][8*ty];
            *(float4*)&a_[4] = *(const float4*)&Xs[kk][8*ty + 4];
            *(float4*)&b_[0] = *(const float4*)&Ws[kk][8*tx];
            *(float4*)&b_[4] = *(const float4*)&Ws[kk][8*tx + 4];
            #pragma unroll
            for (int r = 0; r < 8; ++r)
                #pragma unroll
                for (int c = 0; c < 8; ++c)
                    acc[r][c] = fmaf(a_[r], b_[c], acc[r][c]);
        }
        __syncthreads();
    }

    // epilogue: add bias, store
    float bb[8];
    *(float4*)&bb[0] = *(const float4*)(bias + 8*tx);
    *(float4*)&bb[4] = *(const float4*)(bias + 8*tx + 4);
    #pragma unroll
    for (int r = 0; r < 8; ++r) {
        float4 o0, o1;
        o0.x = acc[r][0] + bb[0]; o0.y = acc[r][1] + bb[1];
        o0.z = acc[r][2] + bb[2]; o0.w = acc[r][3] + bb[3];
        o1.x = acc[r][4] + bb[4]; o1.y = acc[r][5] + bb[5];
        o1.z = acc[r][6] + bb[6]; o1.w = acc[r][7] + bb[7];
        float* op = out + (size_t)(m0 + 8*ty + r)*HDIM + 8*tx;
        *(float4*)op       = o0;
        *(float4*)(op + 4) = o1;
    }
}

// ---------------------------------------------------------------------------
// Kernel 2: flash-style masked attention (fp32), one block per (q-tile, batch)
//   BQ = 64 query rows, iterate K/V in 64-row tiles, online softmax.
//   256 threads, 4x4 per-thread tiles for both QK^T and PV.
// ---------------------------------------------------------------------------
__global__ __launch_bounds__(256)
void attn_kernel(const float* __restrict__ Q, const float* __restrict__ K,
                 const float* __restrict__ V, const int* __restrict__ mask,
                 float* __restrict__ out)
{
    // pad 68 floats (272B = 17*16B) keeps float4 alignment on every row
    __shared__ float Qs[64][68];    // transposed: Qs[d][i]
    __shared__ float KPs[64][68];   // union: K^T as KPs[d][j], then P^T as KPs[j][i]
    __shared__ float Vs[64][68];    // Vs[j][d]
    __shared__ int   maskS[64];

    const int tid = threadIdx.x;
    const int tx  = tid & 15;
    const int ty  = tid >> 4;
    const int b   = blockIdx.y;
    const int s0  = blockIdx.x * 64;

    const size_t bo = (size_t)b * SEQ * HDIM;
    const float* Qb = Q + bo;
    const float* Kb = K + bo;
    const float* Vb = V + bo;

    // Load Q tile (64 x 64) transposed into Qs[d][i]
    {
        const int f4 = tid & 15;
        const int r0 = tid >> 4;
        #pragma unroll
        for (int h = 0; h < 4; ++h) {
            const int i = r0 + 16*h;
            const float4 qv = *(const float4*)(Qb + (size_t)(s0 + i)*HDIM + 4*f4);
            Qs[4*f4+0][i] = qv.x;
            Qs[4*f4+1][i] = qv.y;
            Qs[4*f4+2][i] = qv.z;
            Qs[4*f4+3][i] = qv.w;
        }
    }

    float O[4][4];
    float m_i[4], l_i[4];
    #pragma unroll
    for (int r = 0; r < 4; ++r) {
        m_i[r] = -INFINITY;
        l_i[r] = 0.f;
        #pragma unroll
        for (int c = 0; c < 4; ++c) O[r][c] = 0.f;
    }

    for (int t0 = 0; t0 < SEQ; t0 += 64) {
        __syncthreads();  // prior iteration done reading KPs/Vs (also covers Q store)
        // K tile transposed into KPs[d][j]; V tile direct into Vs[j][d]
        {
            const int f4 = tid & 15;
            const int r0 = tid >> 4;
            #pragma unroll
            for (int h = 0; h < 4; ++h) {
                const int j = r0 + 16*h;
                const float4 kv = *(const float4*)(Kb + (size_t)(t0 + j)*HDIM + 4*f4);
                KPs[4*f4+0][j] = kv.x;
                KPs[4*f4+1][j] = kv.y;
                KPs[4*f4+2][j] = kv.z;
                KPs[4*f4+3][j] = kv.w;
                *(float4*)&Vs[j][4*f4] = *(const float4*)(Vb + (size_t)(t0 + j)*HDIM + 4*f4);
            }
        }
        if (tid < 64) maskS[tid] = mask[b*SEQ + t0 + tid];
        __syncthreads();

        // S = Q @ K^T  (4x4 per thread)
        float s[4][4];
        #pragma unroll
        for (int r = 0; r < 4; ++r)
            #pragma unroll
            for (int c = 0; c < 4; ++c) s[r][c] = 0.f;

        for (int d = 0; d < 64; ++d) {
            float a_[4], b_[4];
            *(float4*)&a_[0] = *(const float4*)&Qs[d][4*ty];
            *(float4*)&b_[0] = *(const float4*)&KPs[d][4*tx];
            #pragma unroll
            for (int r = 0; r < 4; ++r)
                #pragma unroll
                for (int c = 0; c < 4; ++c)
                    s[r][c] = fmaf(a_[r], b_[c], s[r][c]);
        }

        // scale (exact: *0.125f) + mask (matches reference: masked -> -1e9)
        int mk[4];
        #pragma unroll
        for (int c = 0; c < 4; ++c) mk[c] = maskS[4*tx + c];
        #pragma unroll
        for (int r = 0; r < 4; ++r)
            #pragma unroll
            for (int c = 0; c < 4; ++c)
                s[r][c] = mk[c] ? s[r][c] * 0.125f : -1e9f;

        // online softmax: row max across 16 tx lanes (lanes share ty within wave)
        float rowmax[4];
        #pragma unroll
        for (int r = 0; r < 4; ++r)
            rowmax[r] = fmaxf(fmaxf(s[r][0], s[r][1]), fmaxf(s[r][2], s[r][3]));
        #pragma unroll
        for (int off = 8; off; off >>= 1)
            #pragma unroll
            for (int r = 0; r < 4; ++r)
                rowmax[r] = fmaxf(rowmax[r], __shfl_xor(rowmax[r], off, 64));

        float alpha[4], rowsum[4], p[4][4];
        #pragma unroll
        for (int r = 0; r < 4; ++r) {
            const float mnew = fmaxf(m_i[r], rowmax[r]);
            alpha[r] = __expf(m_i[r] - mnew);   // first iter: expf(-inf)=0
            m_i[r] = mnew;
            float rs = 0.f;
            #pragma unroll
            for (int c = 0; c < 4; ++c) {
                p[r][c] = __expf(s[r][c] - mnew);  // masked: exp(-1e9-m) -> 0
                rs += p[r][c];
            }
            rowsum[r] = rs;
        }
        #pragma unroll
        for (int off = 8; off; off >>= 1)
            #pragma unroll
            for (int r = 0; r < 4; ++r)
                rowsum[r] += __shfl_xor(rowsum[r], off, 64);
        #pragma unroll
        for (int r = 0; r < 4; ++r) {
            l_i[r] = l_i[r] * alpha[r] + rowsum[r];
            #pragma unroll
            for (int c = 0; c < 4; ++c) O[r][c] *= alpha[r];
        }

        __syncthreads();  // everyone done reading KPs as K^T
        // store P transposed: KPs[j][i]
        #pragma unroll
        for (int r = 0; r < 4; ++r)
            #pragma unroll
            for (int c = 0; c < 4; ++c)
                KPs[4*tx + c][4*ty + r] = p[r][c];
        __syncthreads();

        // O += P @ V
        for (int j = 0; j < 64; ++j) {
            float ap[4], bv[4];
            *(float4*)&ap[0] = *(const float4*)&KPs[j][4*ty];
            *(float4*)&bv[0] = *(const float4*)&Vs[j][4*tx];
            #pragma unroll
            for (int r = 0; r < 4; ++r)
                #pragma unroll
                for (int c = 0; c < 4; ++c)
                    O[r][c] = fmaf(ap[r], bv[c], O[r][c]);
        }
    }

    // epilogue: normalize and store
    #pragma unroll
    for (int r = 0; r < 4; ++r) {
        const float inv = 1.0f / l_i[r];
        float4 o;
        o.x = O[r][0] * inv; o.y = O[r][1] * inv;
        o.z = O[r][2] * inv; o.w = O[r][3] * inv;
        *(float4*)(out + ((size_t)b*SEQ + s0 + 4*ty + r)*HDIM + 4*tx) = o;
    }
}

// ---------------------------------------------------------------------------
extern "C" void kernel_launch(void* const* d_in, const int* in_sizes, int n_in,
                              void* d_out, int out_size, void* d_ws, size_t ws_size,
                              hipStream_t stream) {
    const float* x    = (const float*)d_in[0];
    const int*   mask = (const int*)  d_in[1];
    const float* Wq   = (const float*)d_in[2];
    const float* bq   = (const float*)d_in[3];
    const float* Wk   = (const float*)d_in[4];
    const float* bk   = (const float*)d_in[5];
    const float* Wv   = (const float*)d_in[6];
    const float* bv   = (const float*)d_in[7];
    float* out = (float*)d_out;

    // workspace: Q,K,V fp32 [MTOT,64] each = 3 * 8 MiB = 25.2 MB
    float* Qb = (float*)d_ws;
    float* Kb = Qb + (size_t)MTOT * HDIM;
    float* Vb = Kb + (size_t)MTOT * HDIM;

    dim3 g1(MTOT / 256, 3), b1(256);
    qkv_proj_kernel<<<g1, b1, 0, stream>>>(x, Wq, bq, Wk, bk, Wv, bv, Qb, Kb, Vb);

    dim3 g2(SEQ / 64, BATCH), b2(256);
    attn_kernel<<<g2, b2, 0, stream>>>(Qb, Kb, Vb, mask, out);
}

// Round 2
// 472.068 us; speedup vs baseline: 1.3635x; 1.3635x over previous
//
#include <hip/hip_runtime.h>
#include <math.h>

#define EMBED 1024
#define HDIM  64
#define BATCH 16
#define SEQ   2048
#define MTOT  (BATCH*SEQ)   // 32768
#define NE    (MTOT*HDIM)   // 2097152 elements per Q/K/V array

typedef __attribute__((ext_vector_type(8))) short short8;   // 8 bf16 (4 VGPR) MFMA A/B frag
typedef __attribute__((ext_vector_type(4))) float float4v;  // MFMA C/D frag

// round-to-nearest-even fp32 -> bf16 (returns bits in low 16)
static __device__ __forceinline__ unsigned int rne_bf16(float f) {
    unsigned int u = __builtin_bit_cast(unsigned int, f);
    return (u + 0x7FFFu + ((u >> 16) & 1u)) >> 16;
}
static __device__ __forceinline__ float bf16_to_f(unsigned int b) {
    return __builtin_bit_cast(float, b << 16);
}
static __device__ __forceinline__ void split2(float x, unsigned int& h, unsigned int& l) {
    h = rne_bf16(x);
    l = rne_bf16(x - bf16_to_f(h));
}

// ---------------------------------------------------------------------------
// Kernel 0: split W into hi/lo bf16, TRANSPOSED: Wt[mat][n][k]  (tiny)
// ---------------------------------------------------------------------------
__global__ void wsplit_kernel(const float* __restrict__ Wq, const float* __restrict__ Wk,
                              const float* __restrict__ Wv,
                              unsigned short* __restrict__ Wth, unsigned short* __restrict__ Wtl)
{
    int e = blockIdx.x * 256 + threadIdx.x;
    if (e >= 3 * EMBED * HDIM) return;
    int mat = e >> 16;          // 65536 per matrix
    int rem = e & 65535;
    int k = rem >> 6;
    int n = rem & 63;
    const float* W = (mat == 0) ? Wq : ((mat == 1) ? Wk : Wv);
    unsigned int h, l;
    split2(W[k * HDIM + n], h, l);
    int di = mat * 65536 + n * EMBED + k;
    Wth[di] = (unsigned short)h;
    Wtl[di] = (unsigned short)l;
}

// ---------------------------------------------------------------------------
// Kernel 1: QKV projection, split-bf16 MFMA.
//   grid (3, MTOT/128); block 128 (2 waves); BM=128 (wave=64 rows), BN=64, BK=32.
//   C = Xh*Wh + Xh*Wl + Xl*Wh  (~fp32 accuracy), bias add, then:
//     mat 0/1 (Q,K): store hi/lo bf16, natural [M][64]
//     mat 2   (V)  : store hi/lo bf16 TRANSPOSED [64][MTOT] via LDS transpose
// ---------------------------------------------------------------------------
__global__ __launch_bounds__(128)
void qkv_mfma_kernel(const float* __restrict__ X,
                     const unsigned short* __restrict__ Wth, const unsigned short* __restrict__ Wtl,
                     const float* __restrict__ bq, const float* __restrict__ bk, const float* __restrict__ bv,
                     unsigned short* __restrict__ Qh, unsigned short* __restrict__ Ql,
                     unsigned short* __restrict__ Kh, unsigned short* __restrict__ Kl,
                     unsigned short* __restrict__ Vth, unsigned short* __restrict__ Vtl)
{
    __shared__ unsigned short Xh[128 * 40];   // [m][k] padded 32->40 shorts (2-way banks only)
    __shared__ unsigned short Xl[128 * 40];
    __shared__ unsigned short Csv[64 * 136];  // V epilogue transpose: [d][m] padded 128->136

    const int tid  = threadIdx.x;
    const int wave = tid >> 6;
    const int lane = tid & 63;
    const int quad = lane >> 4;
    const int c16  = lane & 15;
    const int mat  = blockIdx.x;          // 0=q 1=k 2=v (fastest-varying: X tile L2 reuse)
    const int m0   = blockIdx.y * 128;

    const unsigned short* Wh = Wth + mat * 65536;
    const unsigned short* Wl = Wtl + mat * 65536;

    float4v acc[4][4];
    #pragma unroll
    for (int mt = 0; mt < 4; ++mt)
        #pragma unroll
        for (int nt = 0; nt < 4; ++nt)
            acc[mt][nt] = (float4v){0.f, 0.f, 0.f, 0.f};

    for (int k0 = 0; k0 < EMBED; k0 += 32) {
        __syncthreads();
        // stage X tile 128x32 -> hi/lo bf16 in LDS
        #pragma unroll
        for (int i = 0; i < 8; ++i) {
            int c  = tid + 128 * i;          // 0..1023 float4-chunks
            int m  = c >> 3;
            int ko = (c & 7) * 4;
            float4 xv = *(const float4*)(X + (size_t)(m0 + m) * EMBED + k0 + ko);
            unsigned int h0, l0, h1, l1, h2, l2, h3, l3;
            split2(xv.x, h0, l0); split2(xv.y, h1, l1);
            split2(xv.z, h2, l2); split2(xv.w, h3, l3);
            uint2 hw, lw;
            hw.x = h0 | (h1 << 16); hw.y = h2 | (h3 << 16);
            lw.x = l0 | (l1 << 16); lw.y = l2 | (l3 << 16);
            *(uint2*)&Xh[m * 40 + ko] = hw;
            *(uint2*)&Xl[m * 40 + ko] = lw;
        }
        __syncthreads();

        // B-frags straight from global (L2-resident; B[n][k] = Wt[n][k], k contiguous)
        short8 bh[4], bl[4];
        #pragma unroll
        for (int nt = 0; nt < 4; ++nt) {
            const size_t wo = (size_t)(nt * 16 + c16) * EMBED + k0 + quad * 8;
            bh[nt] = *(const short8*)(Wh + wo);
            bl[nt] = *(const short8*)(Wl + wo);
        }
        // A-frags from LDS + MFMA
        #pragma unroll
        for (int mt = 0; mt < 4; ++mt) {
            const int m = wave * 64 + mt * 16 + c16;
            short8 ah = *(const short8*)&Xh[m * 40 + quad * 8];
            short8 al = *(const short8*)&Xl[m * 40 + quad * 8];
            #pragma unroll
            for (int nt = 0; nt < 4; ++nt) {
                acc[mt][nt] = __builtin_amdgcn_mfma_f32_16x16x32_bf16(ah, bh[nt], acc[mt][nt], 0, 0, 0);
                acc[mt][nt] = __builtin_amdgcn_mfma_f32_16x16x32_bf16(ah, bl[nt], acc[mt][nt], 0, 0, 0);
                acc[mt][nt] = __builtin_amdgcn_mfma_f32_16x16x32_bf16(al, bh[nt], acc[mt][nt], 0, 0, 0);
            }
        }
    }

    const float* bias = (mat == 0) ? bq : ((mat == 1) ? bk : bv);
    float bb[4];
    #pragma unroll
    for (int nt = 0; nt < 4; ++nt) bb[nt] = bias[nt * 16 + c16];

    if (mat < 2) {
        unsigned short* Oh = (mat == 0) ? Qh : Kh;
        unsigned short* Ol = (mat == 0) ? Ql : Kl;
        #pragma unroll
        for (int mt = 0; mt < 4; ++mt)
            #pragma unroll
            for (int nt = 0; nt < 4; ++nt)
                #pragma unroll
                for (int r = 0; r < 4; ++r) {
                    float cv = acc[mt][nt][r] + bb[nt];
                    unsigned int h, l;
                    split2(cv, h, l);
                    size_t row = (size_t)(m0 + wave * 64 + mt * 16 + quad * 4 + r);
                    size_t idx = row * HDIM + nt * 16 + c16;
                    Oh[idx] = (unsigned short)h;
                    Ol[idx] = (unsigned short)l;
                }
    } else {
        // V: transpose through LDS, two passes (hi then lo), coalesced b128 global stores
        #pragma unroll
        for (int sp = 0; sp < 2; ++sp) {
            __syncthreads();
            #pragma unroll
            for (int mt = 0; mt < 4; ++mt)
                #pragma unroll
                for (int nt = 0; nt < 4; ++nt)
                    #pragma unroll
                    for (int r = 0; r < 4; ++r) {
                        float cv = acc[mt][nt][r] + bb[nt];
                        unsigned int h, l;
                        split2(cv, h, l);
                        int d = nt * 16 + c16;
                        int m = wave * 64 + mt * 16 + quad * 4 + r;
                        Csv[d * 136 + m] = (unsigned short)(sp ? l : h);
                    }
            __syncthreads();
            unsigned short* O = sp ? Vtl : Vth;
            int d  = tid >> 1;
            int mo = (tid & 1) * 64;
            #pragma unroll
            for (int j = 0; j < 8; ++j) {
                short8 vv = *(const short8*)&Csv[d * 136 + mo + j * 8];
                *(short8*)(O + (size_t)d * MTOT + m0 + mo + j * 8) = vv;
            }
        }
    }
}

// ---------------------------------------------------------------------------
// Kernel 2: flash attention, split-bf16 MFMA.
//   grid (SEQ/64, BATCH); block 256 (4 waves x 16 q-rows). BKV=64.
//   S = Qh*Kh^T + Qh*Kl^T + Ql*Kh^T ; P bf16 (l_i summed from ROUNDED P);
//   O += P*Vh + P*Vl.  Q frags direct from global; K/V staged in LDS.
// ---------------------------------------------------------------------------
__global__ __launch_bounds__(256)
void attn_mfma_kernel(const unsigned short* __restrict__ Qh, const unsigned short* __restrict__ Ql,
                      const unsigned short* __restrict__ Kh, const unsigned short* __restrict__ Kl,
                      const unsigned short* __restrict__ Vth, const unsigned short* __restrict__ Vtl,
                      const int* __restrict__ mask, float* __restrict__ out)
{
    __shared__ unsigned short Ksh[64 * 72];  // [j][d] pad 64->72 (2-way banks)
    __shared__ unsigned short Ksl[64 * 72];
    __shared__ unsigned short Vsh[64 * 72];  // [d][j] pad
    __shared__ unsigned short Vsl[64 * 72];
    __shared__ unsigned short Ps[4 * 16 * 72]; // per-wave P tile [16 rows][64+8 cols]
    __shared__ int maskS[64];

    const int tid  = threadIdx.x;
    const int wave = tid >> 6;
    const int lane = tid & 63;
    const int quad = lane >> 4;
    const int c16  = lane & 15;
    const int b    = blockIdx.y;
    const int s0   = blockIdx.x * 64;
    const int q0   = s0 + wave * 16;

    // Q fragments: A[m=c16][k=quad*8+j], 2 k-steps x hi/lo — loaded once
    const size_t qrow = (size_t)(b * SEQ + q0 + c16) * HDIM;
    short8 qh0 = *(const short8*)(Qh + qrow + quad * 8);
    short8 qh1 = *(const short8*)(Qh + qrow + 32 + quad * 8);
    short8 ql0 = *(const short8*)(Ql + qrow + quad * 8);
    short8 ql1 = *(const short8*)(Ql + qrow + 32 + quad * 8);

    float4v O[4];
    #pragma unroll
    for (int dt = 0; dt < 4; ++dt) O[dt] = (float4v){0.f, 0.f, 0.f, 0.f};
    float m_i[4], l_i[4];
    #pragma unroll
    for (int r = 0; r < 4; ++r) { m_i[r] = -INFINITY; l_i[r] = 0.f; }

    const size_t kbase = (size_t)b * SEQ * HDIM;  // Kh/Kl are [MTOT][64]
    const int vcol0 = b * SEQ;                    // Vth/Vtl are [64][MTOT]
    const int pbase = wave * 16 * 72;

    for (int t0 = 0; t0 < SEQ; t0 += 64) {
        __syncthreads();
        // stage K (natural) and V^T (already transposed in global) — pure b128 copies
        #pragma unroll
        for (int i = 0; i < 2; ++i) {
            int c = tid + 256 * i;      // 0..511
            int j = c >> 3;
            int o = (c & 7) * 8;
            *(short8*)&Ksh[j * 72 + o] = *(const short8*)(Kh + kbase + (size_t)(t0 + j) * HDIM + o);
            *(short8*)&Ksl[j * 72 + o] = *(const short8*)(Kl + kbase + (size_t)(t0 + j) * HDIM + o);
            *(short8*)&Vsh[j * 72 + o] = *(const short8*)(Vth + (size_t)j * MTOT + vcol0 + t0 + o);
            *(short8*)&Vsl[j * 72 + o] = *(const short8*)(Vtl + (size_t)j * MTOT + vcol0 + t0 + o);
        }
        if (tid < 64) maskS[tid] = mask[b * SEQ + t0 + tid];
        __syncthreads();

        // ---- S = Q K^T (split) ----
        float4v s[4];
        #pragma unroll
        for (int nt = 0; nt < 4; ++nt) {
            const int krow = (nt * 16 + c16) * 72;
            short8 kh0 = *(const short8*)&Ksh[krow + quad * 8];
            short8 kh1 = *(const short8*)&Ksh[krow + 32 + quad * 8];
            short8 kl0 = *(const short8*)&Ksl[krow + quad * 8];
            short8 kl1 = *(const short8*)&Ksl[krow + 32 + quad * 8];
            float4v a = (float4v){0.f, 0.f, 0.f, 0.f};
            a = __builtin_amdgcn_mfma_f32_16x16x32_bf16(qh0, kh0, a, 0, 0, 0);
            a = __builtin_amdgcn_mfma_f32_16x16x32_bf16(qh1, kh1, a, 0, 0, 0);
            a = __builtin_amdgcn_mfma_f32_16x16x32_bf16(qh0, kl0, a, 0, 0, 0);
            a = __builtin_amdgcn_mfma_f32_16x16x32_bf16(qh1, kl1, a, 0, 0, 0);
            a = __builtin_amdgcn_mfma_f32_16x16x32_bf16(ql0, kh0, a, 0, 0, 0);
            a = __builtin_amdgcn_mfma_f32_16x16x32_bf16(ql1, kh1, a, 0, 0, 0);
            s[nt] = a;
        }

        // ---- mask + scale (exact reference semantics) ----
        float p[4][4];  // [nt][r]
        #pragma unroll
        for (int nt = 0; nt < 4; ++nt) {
            int mk = maskS[nt * 16 + c16];
            #pragma unroll
            for (int r = 0; r < 4; ++r)
                p[nt][r] = mk ? s[nt][r] * 0.125f : -1e9f;
        }

        // ---- online softmax (rows live in 16-lane groups; lane owns rows quad*4+r) ----
        float rm[4];
        #pragma unroll
        for (int r = 0; r < 4; ++r)
            rm[r] = fmaxf(fmaxf(p[0][r], p[1][r]), fmaxf(p[2][r], p[3][r]));
        #pragma unroll
        for (int off = 8; off; off >>= 1)
            #pragma unroll
            for (int r = 0; r < 4; ++r)
                rm[r] = fmaxf(rm[r], __shfl_xor(rm[r], off, 64));

        float alpha[4], rs[4];
        #pragma unroll
        for (int r = 0; r < 4; ++r) {
            float mnew = fmaxf(m_i[r], rm[r]);
            alpha[r] = __expf(m_i[r] - mnew);   // first iter: exp(-inf)=0
            m_i[r] = mnew;
            rs[r] = 0.f;
        }
        // exp, round P to bf16; sum the ROUNDED values so renormalization cancels
        #pragma unroll
        for (int nt = 0; nt < 4; ++nt)
            #pragma unroll
            for (int r = 0; r < 4; ++r) {
                float e = __expf(p[nt][r] - m_i[r]);
                unsigned int pb = rne_bf16(e);
                rs[r] += bf16_to_f(pb);
                Ps[pbase + (quad * 4 + r) * 72 + nt * 16 + c16] = (unsigned short)pb;
            }
        #pragma unroll
        for (int off = 8; off; off >>= 1)
            #pragma unroll
            for (int r = 0; r < 4; ++r)
                rs[r] += __shfl_xor(rs[r], off, 64);
        #pragma unroll
        for (int r = 0; r < 4; ++r)
            l_i[r] = l_i[r] * alpha[r] + rs[r];
        #pragma unroll
        for (int dt = 0; dt < 4; ++dt)
            #pragma unroll
            for (int r = 0; r < 4; ++r)
                O[dt][r] *= alpha[r];

        // ---- O += P V (P plain bf16; V split) ----
        const int prow = pbase + c16 * 72;
        short8 pa0 = *(const short8*)&Ps[prow + quad * 8];
        short8 pa1 = *(const short8*)&Ps[prow + 32 + quad * 8];
        #pragma unroll
        for (int dt = 0; dt < 4; ++dt) {
            const int vrow = (dt * 16 + c16) * 72;
            short8 vh0 = *(const short8*)&Vsh[vrow + quad * 8];
            short8 vh1 = *(const short8*)&Vsh[vrow + 32 + quad * 8];
            short8 vl0 = *(const short8*)&Vsl[vrow + quad * 8];
            short8 vl1 = *(const short8*)&Vsl[vrow + 32 + quad * 8];
            O[dt] = __builtin_amdgcn_mfma_f32_16x16x32_bf16(pa0, vh0, O[dt], 0, 0, 0);
            O[dt] = __builtin_amdgcn_mfma_f32_16x16x32_bf16(pa1, vh1, O[dt], 0, 0, 0);
            O[dt] = __builtin_amdgcn_mfma_f32_16x16x32_bf16(pa0, vl0, O[dt], 0, 0, 0);
            O[dt] = __builtin_amdgcn_mfma_f32_16x16x32_bf16(pa1, vl1, O[dt], 0, 0, 0);
        }
    }

    // epilogue: normalize, store fp32 (C-layout: row=quad*4+r, col=dt*16+c16)
    #pragma unroll
    for (int r = 0; r < 4; ++r) {
        float inv = 1.0f / l_i[r];
        size_t orow = (size_t)(b * SEQ + q0 + quad * 4 + r) * HDIM;
        #pragma unroll
        for (int dt = 0; dt < 4; ++dt)
            out[orow + dt * 16 + c16] = O[dt][r] * inv;
    }
}

// ---------------------------------------------------------------------------
extern "C" void kernel_launch(void* const* d_in, const int* in_sizes, int n_in,
                              void* d_out, int out_size, void* d_ws, size_t ws_size,
                              hipStream_t stream) {
    const float* x    = (const float*)d_in[0];
    const int*   mask = (const int*)  d_in[1];
    const float* Wq   = (const float*)d_in[2];
    const float* bq   = (const float*)d_in[3];
    const float* Wk   = (const float*)d_in[4];
    const float* bk   = (const float*)d_in[5];
    const float* Wv   = (const float*)d_in[6];
    const float* bv   = (const float*)d_in[7];
    float* out = (float*)d_out;

    // workspace: 6 bf16 arrays of NE shorts = 24 MB
    unsigned short* base = (unsigned short*)d_ws;
    unsigned short* Qh  = base + 0 * (size_t)NE;
    unsigned short* Ql  = base + 1 * (size_t)NE;
    unsigned short* Kh  = base + 2 * (size_t)NE;
    unsigned short* Kl  = base + 3 * (size_t)NE;
    unsigned short* Vth = base + 4 * (size_t)NE;
    unsigned short* Vtl = base + 5 * (size_t)NE;
    // W splits parked in d_out (768 KB of 8 MB); consumed before attn overwrites out
    unsigned short* Wth = (unsigned short*)d_out;
    unsigned short* Wtl = Wth + 3 * 65536;

    wsplit_kernel<<<dim3(768), dim3(256), 0, stream>>>(Wq, Wk, Wv, Wth, Wtl);

    dim3 g1(3, MTOT / 128), b1(128);
    qkv_mfma_kernel<<<g1, b1, 0, stream>>>(x, Wth, Wtl, bq, bk, bv,
                                           Qh, Ql, Kh, Kl, Vth, Vtl);

    dim3 g2(SEQ / 64, BATCH), b2(256);
    attn_mfma_kernel<<<g2, b2, 0, stream>>>(Qh, Ql, Kh, Kl, Vth, Vtl, mask, out);
}

// Round 3
// 302.817 us; speedup vs baseline: 2.1255x; 1.5589x over previous
//
#include <hip/hip_runtime.h>
#include <math.h>

#define EMBED 1024
#define HDIM  64
#define BATCH 16
#define SEQ   2048
#define MTOT  (BATCH*SEQ)   // 32768
#define NE    (MTOT*HDIM)   // elements per Q/K/V array

typedef __attribute__((ext_vector_type(8))) short short8;   // 8 bf16 MFMA A/B frag
typedef __attribute__((ext_vector_type(4))) float float4v;  // MFMA C/D frag

// round-to-nearest-even fp32 -> bf16 (bits in low 16)
static __device__ __forceinline__ unsigned int rne_bf16(float f) {
    unsigned int u = __builtin_bit_cast(unsigned int, f);
    return (u + 0x7FFFu + ((u >> 16) & 1u)) >> 16;
}
static __device__ __forceinline__ float bf16_to_f(unsigned int b) {
    return __builtin_bit_cast(float, b << 16);
}
static __device__ __forceinline__ void split2(float x, unsigned int& h, unsigned int& l) {
    h = rne_bf16(x);
    l = rne_bf16(x - bf16_to_f(h));
}

// ---------------------------------------------------------------------------
// Kernel 0: split W into hi/lo bf16, transposed+concatenated: Wt[192][1024]
//   global col gn in [0,192): mat = gn>>6, n = gn&63. Coalesced writes.
// ---------------------------------------------------------------------------
__global__ void wsplit_kernel(const float* __restrict__ Wq, const float* __restrict__ Wk,
                              const float* __restrict__ Wv,
                              unsigned short* __restrict__ Wth, unsigned short* __restrict__ Wtl)
{
    int e = blockIdx.x * 256 + threadIdx.x;     // e = gn*1024 + k
    if (e >= 192 * EMBED) return;
    int gn = e >> 10;
    int k  = e & 1023;
    int mat = gn >> 6;
    int n   = gn & 63;
    const float* W = (mat == 0) ? Wq : ((mat == 1) ? Wk : Wv);
    unsigned int h, l;
    split2(W[k * HDIM + n], h, l);
    Wth[e] = (unsigned short)h;
    Wtl[e] = (unsigned short)l;
}

// ---------------------------------------------------------------------------
// Kernel 1: fused QKV projection, split-bf16 MFMA.
//   grid 512 (MTOT/64); block 256 = 4 waves. BM=64 (all waves), each wave
//   covers 48 of the 192 output cols (nt = wave*3+0..2). BK=64, 16 k-iters,
//   register-prefetch double buffering of the X tile.
//   C = Xh*Wh + Xh*Wl + Xl*Wh, bias; Q/K stored natural hi/lo bf16,
//   V stored TRANSPOSED [64][MTOT] hi/lo via LDS transpose.
// ---------------------------------------------------------------------------
__global__ __launch_bounds__(256)
void qkv_mfma_kernel(const float* __restrict__ X,
                     const unsigned short* __restrict__ Wth, const unsigned short* __restrict__ Wtl,
                     const float* __restrict__ bq, const float* __restrict__ bk, const float* __restrict__ bv,
                     unsigned short* __restrict__ Qh, unsigned short* __restrict__ Ql,
                     unsigned short* __restrict__ Kh, unsigned short* __restrict__ Kl,
                     unsigned short* __restrict__ Vth, unsigned short* __restrict__ Vtl)
{
    __shared__ unsigned short Xh[64 * 72];   // [m][k] pad 64->72 shorts (2-way banks = free)
    __shared__ unsigned short Xl[64 * 72];
    __shared__ unsigned short Csv[64 * 72];  // V epilogue transpose [d][m]

    const int tid  = threadIdx.x;
    const int wave = tid >> 6;
    const int lane = tid & 63;
    const int quad = lane >> 4;
    const int c16  = lane & 15;
    const int m0   = blockIdx.x * 64;
    const int gnb  = wave * 3;               // first nt of this wave

    float4v acc[4][3];
    #pragma unroll
    for (int mt = 0; mt < 4; ++mt)
        #pragma unroll
        for (int nt = 0; nt < 3; ++nt)
            acc[mt][nt] = (float4v){0.f, 0.f, 0.f, 0.f};

    // prefetch tile 0: 64 rows x 64 k fp32 = 16 KB -> 4 float4 per thread
    float4 pf[4];
    #pragma unroll
    for (int i = 0; i < 4; ++i) {
        int c = tid + 256 * i, m = c >> 4, ko = (c & 15) * 4;
        pf[i] = *(const float4*)(X + (size_t)(m0 + m) * EMBED + ko);
    }

    for (int k0 = 0; k0 < EMBED; k0 += 64) {
        __syncthreads();
        // split + store staged regs to LDS
        #pragma unroll
        for (int i = 0; i < 4; ++i) {
            int c = tid + 256 * i, m = c >> 4, ko = (c & 15) * 4;
            unsigned int h0, l0, h1, l1, h2, l2, h3, l3;
            split2(pf[i].x, h0, l0); split2(pf[i].y, h1, l1);
            split2(pf[i].z, h2, l2); split2(pf[i].w, h3, l3);
            uint2 hw, lw;
            hw.x = h0 | (h1 << 16); hw.y = h2 | (h3 << 16);
            lw.x = l0 | (l1 << 16); lw.y = l2 | (l3 << 16);
            *(uint2*)&Xh[m * 72 + ko] = hw;
            *(uint2*)&Xl[m * 72 + ko] = lw;
        }
        __syncthreads();

        // issue next tile's loads (latency hides under this tile's MFMA)
        {
            int k1 = (k0 + 64) & (EMBED - 1);
            #pragma unroll
            for (int i = 0; i < 4; ++i) {
                int c = tid + 256 * i, m = c >> 4, ko = (c & 15) * 4;
                pf[i] = *(const float4*)(X + (size_t)(m0 + m) * EMBED + k1 + ko);
            }
        }

        #pragma unroll
        for (int ks = 0; ks < 2; ++ks) {
            short8 ah[4], al[4];
            #pragma unroll
            for (int mt = 0; mt < 4; ++mt) {
                const int xo = (mt * 16 + c16) * 72 + ks * 32 + quad * 8;
                ah[mt] = *(const short8*)&Xh[xo];
                al[mt] = *(const short8*)&Xl[xo];
            }
            short8 bh[3], bl[3];
            #pragma unroll
            for (int nt = 0; nt < 3; ++nt) {
                const size_t wo = (size_t)((gnb + nt) * 16 + c16) * EMBED + k0 + ks * 32 + quad * 8;
                bh[nt] = *(const short8*)(Wth + wo);
                bl[nt] = *(const short8*)(Wtl + wo);
            }
            #pragma unroll
            for (int mt = 0; mt < 4; ++mt)
                #pragma unroll
                for (int nt = 0; nt < 3; ++nt) {
                    acc[mt][nt] = __builtin_amdgcn_mfma_f32_16x16x32_bf16(ah[mt], bh[nt], acc[mt][nt], 0, 0, 0);
                    acc[mt][nt] = __builtin_amdgcn_mfma_f32_16x16x32_bf16(ah[mt], bl[nt], acc[mt][nt], 0, 0, 0);
                    acc[mt][nt] = __builtin_amdgcn_mfma_f32_16x16x32_bf16(al[mt], bh[nt], acc[mt][nt], 0, 0, 0);
                }
        }
    }

    // bias per nt (bias is tiny; L2-hot)
    float bb[3];
    #pragma unroll
    for (int nt = 0; nt < 3; ++nt) {
        int gn = (gnb + nt) * 16 + c16, mat = gn >> 6, cn = gn & 63;
        bb[nt] = ((mat == 0) ? bq : ((mat == 1) ? bk : bv))[cn];
    }

    // Q/K: direct hi/lo stores
    #pragma unroll
    for (int mt = 0; mt < 4; ++mt)
        #pragma unroll
        for (int nt = 0; nt < 3; ++nt) {
            int gn = (gnb + nt) * 16 + c16, mat = gn >> 6, cn = gn & 63;
            if (mat < 2) {
                unsigned short* Oh = mat ? Kh : Qh;
                unsigned short* Ol = mat ? Kl : Ql;
                #pragma unroll
                for (int r = 0; r < 4; ++r) {
                    float cv = acc[mt][nt][r] + bb[nt];
                    unsigned int h, l;
                    split2(cv, h, l);
                    size_t idx = (size_t)(m0 + mt * 16 + quad * 4 + r) * HDIM + cn;
                    Oh[idx] = (unsigned short)h;
                    Ol[idx] = (unsigned short)l;
                }
            }
        }

    // V: two transpose passes (hi, lo) through Csv, coalesced b128 stores
    #pragma unroll
    for (int sp = 0; sp < 2; ++sp) {
        __syncthreads();
        #pragma unroll
        for (int mt = 0; mt < 4; ++mt)
            #pragma unroll
            for (int nt = 0; nt < 3; ++nt) {
                int gn = (gnb + nt) * 16 + c16, mat = gn >> 6, cn = gn & 63;
                if (mat == 2) {
                    #pragma unroll
                    for (int r = 0; r < 4; ++r) {
                        float cv = acc[mt][nt][r] + bb[nt];
                        unsigned int h, l;
                        split2(cv, h, l);
                        Csv[cn * 72 + mt * 16 + quad * 4 + r] = (unsigned short)(sp ? l : h);
                    }
                }
            }
        __syncthreads();
        unsigned short* O = sp ? Vtl : Vth;
        int d = tid >> 2, ms = (tid & 3) * 16;
        #pragma unroll
        for (int j = 0; j < 2; ++j)
            *(short8*)(O + (size_t)d * MTOT + m0 + ms + 8 * j) =
                *(const short8*)&Csv[d * 72 + ms + 8 * j];
    }
}

// ---------------------------------------------------------------------------
// Kernel 2: flash attention, split-bf16 MFMA, fixed-shift softmax.
//   grid (SEQ/64, BATCH); block 256 (4 waves x 16 q-rows). BKV=64.
//   Register-prefetch double buffering of K/V tiles.
//   S = Qh*Kh + Qh*Kl + Ql*Kh ; p = exp(s/8 - 12) (shift-invariant, masked->0);
//   l accumulated by MFMA vs all-ones B-frag; O += P*Vh + P*Vl.
// ---------------------------------------------------------------------------
__global__ __launch_bounds__(256)
void attn_mfma_kernel(const unsigned short* __restrict__ Qh, const unsigned short* __restrict__ Ql,
                      const unsigned short* __restrict__ Kh, const unsigned short* __restrict__ Kl,
                      const unsigned short* __restrict__ Vth, const unsigned short* __restrict__ Vtl,
                      const int* __restrict__ mask, float* __restrict__ out)
{
    __shared__ unsigned short Ksh[64 * 72];  // [j][d] pad (2-way banks = free)
    __shared__ unsigned short Ksl[64 * 72];
    __shared__ unsigned short Vsh[64 * 72];  // [d][j]
    __shared__ unsigned short Vsl[64 * 72];
    __shared__ unsigned short Ps[4 * 16 * 72]; // per-wave P tile (wave-private)
    __shared__ int maskS[64];

    const int tid  = threadIdx.x;
    const int wave = tid >> 6;
    const int lane = tid & 63;
    const int quad = lane >> 4;
    const int c16  = lane & 15;
    const int b    = blockIdx.y;
    const int s0   = blockIdx.x * 64;
    const int q0   = s0 + wave * 16;

    // Q fragments (A-layout), loaded once
    const size_t qrow = (size_t)(b * SEQ + q0 + c16) * HDIM;
    short8 qh0 = *(const short8*)(Qh + qrow + quad * 8);
    short8 qh1 = *(const short8*)(Qh + qrow + 32 + quad * 8);
    short8 ql0 = *(const short8*)(Ql + qrow + quad * 8);
    short8 ql1 = *(const short8*)(Ql + qrow + 32 + quad * 8);

    const short8 ones = {0x3F80, 0x3F80, 0x3F80, 0x3F80, 0x3F80, 0x3F80, 0x3F80, 0x3F80};

    float4v O[4];
    #pragma unroll
    for (int dt = 0; dt < 4; ++dt) O[dt] = (float4v){0.f, 0.f, 0.f, 0.f};
    float4v lacc = (float4v){0.f, 0.f, 0.f, 0.f};

    const size_t kbase = (size_t)b * SEQ * HDIM;   // Kh/Kl: [MTOT][64]
    const int vcol0 = b * SEQ;                     // Vth/Vtl: [64][MTOT]
    const int pbase = wave * 16 * 72;

    // prefetch tile 0: per thread 2 chunk positions x 4 arrays
    short8 pfK[2], pfKl[2], pfV[2], pfVl[2];
    int mreg;
    {
        #pragma unroll
        for (int i = 0; i < 2; ++i) {
            int c = tid + 256 * i, j = c >> 3, o = (c & 7) * 8;
            pfK[i]  = *(const short8*)(Kh  + kbase + (size_t)j * HDIM + o);
            pfKl[i] = *(const short8*)(Kl  + kbase + (size_t)j * HDIM + o);
            pfV[i]  = *(const short8*)(Vth + (size_t)j * MTOT + vcol0 + o);
            pfVl[i] = *(const short8*)(Vtl + (size_t)j * MTOT + vcol0 + o);
        }
        mreg = mask[b * SEQ + (tid & 63)];
    }

    for (int t0 = 0; t0 < SEQ; t0 += 64) {
        __syncthreads();
        #pragma unroll
        for (int i = 0; i < 2; ++i) {
            int c = tid + 256 * i, j = c >> 3, o = (c & 7) * 8;
            *(short8*)&Ksh[j * 72 + o] = pfK[i];
            *(short8*)&Ksl[j * 72 + o] = pfKl[i];
            *(short8*)&Vsh[j * 72 + o] = pfV[i];
            *(short8*)&Vsl[j * 72 + o] = pfVl[i];
        }
        if (tid < 64) maskS[tid] = mreg;
        __syncthreads();

        // issue next-tile loads (wrap on last iter; results discarded)
        {
            int t1 = (t0 + 64) & (SEQ - 1);
            #pragma unroll
            for (int i = 0; i < 2; ++i) {
                int c = tid + 256 * i, j = c >> 3, o = (c & 7) * 8;
                pfK[i]  = *(const short8*)(Kh  + kbase + (size_t)(t1 + j) * HDIM + o);
                pfKl[i] = *(const short8*)(Kl  + kbase + (size_t)(t1 + j) * HDIM + o);
                pfV[i]  = *(const short8*)(Vth + (size_t)j * MTOT + vcol0 + t1 + o);
                pfVl[i] = *(const short8*)(Vtl + (size_t)j * MTOT + vcol0 + t1 + o);
            }
            mreg = mask[b * SEQ + t1 + (tid & 63)];
        }

        // ---- S = Q K^T (split, 6 MFMA per nt) ----
        float4v s[4];
        #pragma unroll
        for (int nt = 0; nt < 4; ++nt) {
            const int krow = (nt * 16 + c16) * 72;
            short8 kh0 = *(const short8*)&Ksh[krow + quad * 8];
            short8 kh1 = *(const short8*)&Ksh[krow + 32 + quad * 8];
            short8 kl0 = *(const short8*)&Ksl[krow + quad * 8];
            short8 kl1 = *(const short8*)&Ksl[krow + 32 + quad * 8];
            float4v a = (float4v){0.f, 0.f, 0.f, 0.f};
            a = __builtin_amdgcn_mfma_f32_16x16x32_bf16(qh0, kh0, a, 0, 0, 0);
            a = __builtin_amdgcn_mfma_f32_16x16x32_bf16(qh1, kh1, a, 0, 0, 0);
            a = __builtin_amdgcn_mfma_f32_16x16x32_bf16(qh0, kl0, a, 0, 0, 0);
            a = __builtin_amdgcn_mfma_f32_16x16x32_bf16(qh1, kl1, a, 0, 0, 0);
            a = __builtin_amdgcn_mfma_f32_16x16x32_bf16(ql0, kh0, a, 0, 0, 0);
            a = __builtin_amdgcn_mfma_f32_16x16x32_bf16(ql1, kh1, a, 0, 0, 0);
            s[nt] = a;
        }

        // ---- fixed-shift softmax: p = exp(s*0.125 - 12), masked -> 0 ----
        #pragma unroll
        for (int nt = 0; nt < 4; ++nt) {
            int mk = maskS[nt * 16 + c16];
            #pragma unroll
            for (int r = 0; r < 4; ++r) {
                float t = fmaf(s[nt][r], 0.125f, -12.0f);
                t = mk ? t : -1e30f;                 // exp -> exact 0
                float e = __expf(t);
                Ps[pbase + (quad * 4 + r) * 72 + nt * 16 + c16] =
                    (unsigned short)rne_bf16(e);
            }
        }

        // ---- P frags; l-sum via MFMA vs ones; O += P V ----
        const int prow = pbase + c16 * 72;
        short8 pa0 = *(const short8*)&Ps[prow + quad * 8];
        short8 pa1 = *(const short8*)&Ps[prow + 32 + quad * 8];
        lacc = __builtin_amdgcn_mfma_f32_16x16x32_bf16(pa0, ones, lacc, 0, 0, 0);
        lacc = __builtin_amdgcn_mfma_f32_16x16x32_bf16(pa1, ones, lacc, 0, 0, 0);
        #pragma unroll
        for (int dt = 0; dt < 4; ++dt) {
            const int vrow = (dt * 16 + c16) * 72;
            short8 vh0 = *(const short8*)&Vsh[vrow + quad * 8];
            short8 vh1 = *(const short8*)&Vsh[vrow + 32 + quad * 8];
            short8 vl0 = *(const short8*)&Vsl[vrow + quad * 8];
            short8 vl1 = *(const short8*)&Vsl[vrow + 32 + quad * 8];
            O[dt] = __builtin_amdgcn_mfma_f32_16x16x32_bf16(pa0, vh0, O[dt], 0, 0, 0);
            O[dt] = __builtin_amdgcn_mfma_f32_16x16x32_bf16(pa1, vh1, O[dt], 0, 0, 0);
            O[dt] = __builtin_amdgcn_mfma_f32_16x16x32_bf16(pa0, vl0, O[dt], 0, 0, 0);
            O[dt] = __builtin_amdgcn_mfma_f32_16x16x32_bf16(pa1, vl1, O[dt], 0, 0, 0);
        }
    }

    // epilogue: normalize, store fp32 (C-layout: row=quad*4+r, col=dt*16+c16)
    #pragma unroll
    for (int r = 0; r < 4; ++r) {
        float inv = 1.0f / lacc[r];
        size_t orow = (size_t)(b * SEQ + q0 + quad * 4 + r) * HDIM;
        #pragma unroll
        for (int dt = 0; dt < 4; ++dt)
            out[orow + dt * 16 + c16] = O[dt][r] * inv;
    }
}

// ---------------------------------------------------------------------------
extern "C" void kernel_launch(void* const* d_in, const int* in_sizes, int n_in,
                              void* d_out, int out_size, void* d_ws, size_t ws_size,
                              hipStream_t stream) {
    const float* x    = (const float*)d_in[0];
    const int*   mask = (const int*)  d_in[1];
    const float* Wq   = (const float*)d_in[2];
    const float* bq   = (const float*)d_in[3];
    const float* Wk   = (const float*)d_in[4];
    const float* bk   = (const float*)d_in[5];
    const float* Wv   = (const float*)d_in[6];
    const float* bv   = (const float*)d_in[7];
    float* out = (float*)d_out;

    unsigned short* base = (unsigned short*)d_ws;
    unsigned short* Qh  = base + 0 * (size_t)NE;
    unsigned short* Ql  = base + 1 * (size_t)NE;
    unsigned short* Kh  = base + 2 * (size_t)NE;
    unsigned short* Kl  = base + 3 * (size_t)NE;
    unsigned short* Vth = base + 4 * (size_t)NE;
    unsigned short* Vtl = base + 5 * (size_t)NE;
    // W splits parked in d_out (768 KB of 8 MB); consumed before attn writes out
    unsigned short* Wth = (unsigned short*)d_out;
    unsigned short* Wtl = Wth + 192 * EMBED;

    wsplit_kernel<<<dim3(768), dim3(256), 0, stream>>>(Wq, Wk, Wv, Wth, Wtl);

    qkv_mfma_kernel<<<dim3(MTOT / 64), dim3(256), 0, stream>>>(
        x, Wth, Wtl, bq, bk, bv, Qh, Ql, Kh, Kl, Vth, Vtl);

    attn_mfma_kernel<<<dim3(SEQ / 64, BATCH), dim3(256), 0, stream>>>(
        Qh, Ql, Kh, Kl, Vth, Vtl, mask, out);
}

// Round 4
// 261.591 us; speedup vs baseline: 2.4605x; 1.1576x over previous
//
#include <hip/hip_runtime.h>
#include <math.h>

#define EMBED 1024
#define HDIM  64
#define BATCH 16
#define SEQ   2048
#define MTOT  (BATCH*SEQ)   // 32768
#define NE    (MTOT*HDIM)   // elements per Q/K/V array

typedef _Float16 f16;
typedef __attribute__((ext_vector_type(8))) _Float16 half8;  // 4 VGPR MFMA A/B frag
typedef __attribute__((ext_vector_type(4))) _Float16 half4;  // 8B LDS store
typedef __attribute__((ext_vector_type(4))) float  float4v;  // MFMA C/D frag

// ---------------------------------------------------------------------------
// Kernel 0: W -> fp16, transposed+concatenated: Wt[192][1024] (tiny)
// ---------------------------------------------------------------------------
__global__ void wprep_kernel(const float* __restrict__ Wq, const float* __restrict__ Wk,
                             const float* __restrict__ Wv, f16* __restrict__ Wt)
{
    int e = blockIdx.x * 256 + threadIdx.x;     // e = gn*1024 + k
    if (e >= 192 * EMBED) return;
    int gn = e >> 10, k = e & 1023;
    int mat = gn >> 6, n = gn & 63;
    const float* W = (mat == 0) ? Wq : ((mat == 1) ? Wk : Wv);
    Wt[e] = (f16)W[k * HDIM + n];
}

// ---------------------------------------------------------------------------
// Kernel 1: fused QKV projection, fp16 MFMA (single precision-level: output
//   is fp16 anyway, so fp16 inputs cost ~nothing extra numerically).
//   grid MTOT/64; block 256 = 4 waves; BM=64, each wave 48 of 192 cols.
//   BK=64, 16 k-iters; X register-prefetch; W frags hoisted before barrier.
//   Q,K stored [M][64] fp16; V stored transposed [64][MTOT] fp16.
// ---------------------------------------------------------------------------
__global__ __launch_bounds__(256)
void qkv_mfma_kernel(const float* __restrict__ X, const f16* __restrict__ Wt,
                     const float* __restrict__ bq, const float* __restrict__ bk, const float* __restrict__ bv,
                     f16* __restrict__ Q, f16* __restrict__ K, f16* __restrict__ Vt)
{
    __shared__ f16 Xs[64 * 72];    // [m][k] pad 64->72 halves (<=2-way banks)
    __shared__ f16 Csv[64 * 72];   // V epilogue transpose [d][m]

    const int tid  = threadIdx.x;
    const int wave = tid >> 6;
    const int lane = tid & 63;
    const int quad = lane >> 4;
    const int c16  = lane & 15;
    const int m0   = blockIdx.x * 64;
    const int gnb  = wave * 3;

    float4v acc[4][3];
    #pragma unroll
    for (int mt = 0; mt < 4; ++mt)
        #pragma unroll
        for (int nt = 0; nt < 3; ++nt)
            acc[mt][nt] = (float4v){0.f, 0.f, 0.f, 0.f};

    // prefetch X tile 0 (64x64 fp32 = 16 KB -> 4 float4/thread)
    float4 pf[4];
    #pragma unroll
    for (int i = 0; i < 4; ++i) {
        int c = tid + 256 * i, m = c >> 4, ko = (c & 15) * 4;
        pf[i] = *(const float4*)(X + (size_t)(m0 + m) * EMBED + ko);
    }

    for (int k0 = 0; k0 < EMBED; k0 += 64) {
        // B-frags for this iter (L2-hot W) — issued before the barrier so the
        // ~200-cyc L2 latency hides under barrier + LDS store
        half8 bh[2][3];
        #pragma unroll
        for (int ks = 0; ks < 2; ++ks)
            #pragma unroll
            for (int nt = 0; nt < 3; ++nt)
                bh[ks][nt] = *(const half8*)(Wt + (size_t)((gnb + nt) * 16 + c16) * EMBED
                                             + k0 + ks * 32 + quad * 8);

        __syncthreads();
        #pragma unroll
        for (int i = 0; i < 4; ++i) {
            int c = tid + 256 * i, m = c >> 4, ko = (c & 15) * 4;
            half4 h = { (f16)pf[i].x, (f16)pf[i].y, (f16)pf[i].z, (f16)pf[i].w };
            *(half4*)&Xs[m * 72 + ko] = h;
        }
        __syncthreads();

        // prefetch next X tile
        {
            int k1 = (k0 + 64) & (EMBED - 1);
            #pragma unroll
            for (int i = 0; i < 4; ++i) {
                int c = tid + 256 * i, m = c >> 4, ko = (c & 15) * 4;
                pf[i] = *(const float4*)(X + (size_t)(m0 + m) * EMBED + k1 + ko);
            }
        }

        #pragma unroll
        for (int ks = 0; ks < 2; ++ks) {
            half8 a[4];
            #pragma unroll
            for (int mt = 0; mt < 4; ++mt)
                a[mt] = *(const half8*)&Xs[(mt * 16 + c16) * 72 + ks * 32 + quad * 8];
            #pragma unroll
            for (int mt = 0; mt < 4; ++mt)
                #pragma unroll
                for (int nt = 0; nt < 3; ++nt)
                    acc[mt][nt] = __builtin_amdgcn_mfma_f32_16x16x32_f16(a[mt], bh[ks][nt], acc[mt][nt], 0, 0, 0);
        }
    }

    // bias (uniform per (wave,nt) 16-col tile lies inside one matrix)
    float bb[3];
    #pragma unroll
    for (int nt = 0; nt < 3; ++nt) {
        int gn = (gnb + nt) * 16 + c16, mat = gn >> 6, cn = gn & 63;
        bb[nt] = ((mat == 0) ? bq : ((mat == 1) ? bk : bv))[cn];
    }

    // Q/K: direct fp16 stores
    #pragma unroll
    for (int mt = 0; mt < 4; ++mt)
        #pragma unroll
        for (int nt = 0; nt < 3; ++nt) {
            int gn = (gnb + nt) * 16 + c16, mat = gn >> 6, cn = gn & 63;
            if (mat < 2) {
                f16* O = mat ? K : Q;
                #pragma unroll
                for (int r = 0; r < 4; ++r)
                    O[(size_t)(m0 + mt * 16 + quad * 4 + r) * HDIM + cn] =
                        (f16)(acc[mt][nt][r] + bb[nt]);
            }
        }

    // V: transpose through LDS, coalesced half8 stores
    __syncthreads();
    #pragma unroll
    for (int mt = 0; mt < 4; ++mt)
        #pragma unroll
        for (int nt = 0; nt < 3; ++nt) {
            int gn = (gnb + nt) * 16 + c16, mat = gn >> 6, cn = gn & 63;
            if (mat == 2) {
                #pragma unroll
                for (int r = 0; r < 4; ++r)
                    Csv[cn * 72 + mt * 16 + quad * 4 + r] = (f16)(acc[mt][nt][r] + bb[nt]);
            }
        }
    __syncthreads();
    {
        int d = tid >> 2, ms = (tid & 3) * 16;
        #pragma unroll
        for (int j = 0; j < 2; ++j)
            *(half8*)(Vt + (size_t)d * MTOT + m0 + ms + 8 * j) =
                *(const half8*)&Csv[d * 72 + ms + 8 * j];
    }
}

// ---------------------------------------------------------------------------
// Kernel 2: flash attention, fp16 MFMA, fixed-shift softmax.
//   grid (SEQ/64, BATCH); block 256 (4 waves x 16 q-rows); BKV=64.
//   K/V register-prefetch double buffering.
//   S = Q K^T (2 MFMA/tile); p = exp(s/8 - 6) (shift-invariant; fp16-normal
//   range; masked -> exact 0); l via MFMA vs ones; O += P V (2 MFMA/tile).
// ---------------------------------------------------------------------------
__global__ __launch_bounds__(256)
void attn_mfma_kernel(const f16* __restrict__ Q, const f16* __restrict__ K,
                      const f16* __restrict__ Vt, const int* __restrict__ mask,
                      float* __restrict__ out)
{
    __shared__ f16 Ks[64 * 72];      // [j][d] pad (<=2-way banks)
    __shared__ f16 Vs[64 * 72];      // [d][j]
    __shared__ f16 Ps[4 * 16 * 72];  // per-wave P tile
    __shared__ int maskS[64];

    const int tid  = threadIdx.x;
    const int wave = tid >> 6;
    const int lane = tid & 63;
    const int quad = lane >> 4;
    const int c16  = lane & 15;
    const int b    = blockIdx.y;
    const int s0   = blockIdx.x * 64;
    const int q0   = s0 + wave * 16;

    // Q A-frags, loaded once
    const size_t qrow = (size_t)(b * SEQ + q0 + c16) * HDIM;
    half8 qa0 = *(const half8*)(Q + qrow + quad * 8);
    half8 qa1 = *(const half8*)(Q + qrow + 32 + quad * 8);

    const half8 ones = { (f16)1.f, (f16)1.f, (f16)1.f, (f16)1.f,
                         (f16)1.f, (f16)1.f, (f16)1.f, (f16)1.f };

    float4v O[4];
    #pragma unroll
    for (int dt = 0; dt < 4; ++dt) O[dt] = (float4v){0.f, 0.f, 0.f, 0.f};
    float4v lacc = (float4v){0.f, 0.f, 0.f, 0.f};

    const size_t kbase = (size_t)b * SEQ * HDIM;   // K: [MTOT][64]
    const int vcol0 = b * SEQ;                     // Vt: [64][MTOT]
    const int pbase = wave * 16 * 72;

    // prefetch tile 0
    half8 pfK[2], pfV[2];
    int mreg;
    #pragma unroll
    for (int i = 0; i < 2; ++i) {
        int c = tid + 256 * i, j = c >> 3, o = (c & 7) * 8;
        pfK[i] = *(const half8*)(K  + kbase + (size_t)j * HDIM + o);
        pfV[i] = *(const half8*)(Vt + (size_t)j * MTOT + vcol0 + o);
    }
    mreg = mask[b * SEQ + (tid & 63)];

    for (int t0 = 0; t0 < SEQ; t0 += 64) {
        __syncthreads();
        #pragma unroll
        for (int i = 0; i < 2; ++i) {
            int c = tid + 256 * i, j = c >> 3, o = (c & 7) * 8;
            *(half8*)&Ks[j * 72 + o] = pfK[i];
            *(half8*)&Vs[j * 72 + o] = pfV[i];
        }
        if (tid < 64) maskS[tid] = mreg;
        __syncthreads();

        // next-tile prefetch (wrap on last iter; discarded)
        {
            int t1 = (t0 + 64) & (SEQ - 1);
            #pragma unroll
            for (int i = 0; i < 2; ++i) {
                int c = tid + 256 * i, j = c >> 3, o = (c & 7) * 8;
                pfK[i] = *(const half8*)(K  + kbase + (size_t)(t1 + j) * HDIM + o);
                pfV[i] = *(const half8*)(Vt + (size_t)j * MTOT + vcol0 + t1 + o);
            }
            mreg = mask[b * SEQ + t1 + (tid & 63)];
        }

        // ---- S = Q K^T ----
        float4v s[4];
        #pragma unroll
        for (int nt = 0; nt < 4; ++nt) {
            const int krow = (nt * 16 + c16) * 72;
            half8 kh0 = *(const half8*)&Ks[krow + quad * 8];
            half8 kh1 = *(const half8*)&Ks[krow + 32 + quad * 8];
            float4v a = (float4v){0.f, 0.f, 0.f, 0.f};
            a = __builtin_amdgcn_mfma_f32_16x16x32_f16(qa0, kh0, a, 0, 0, 0);
            a = __builtin_amdgcn_mfma_f32_16x16x32_f16(qa1, kh1, a, 0, 0, 0);
            s[nt] = a;
        }

        // ---- p = exp(s/8 - 6); masked -> exact 0; store fp16 ----
        #pragma unroll
        for (int nt = 0; nt < 4; ++nt) {
            int mk = maskS[nt * 16 + c16];
            #pragma unroll
            for (int r = 0; r < 4; ++r) {
                float t = fmaf(s[nt][r], 0.125f, -6.0f);
                t = mk ? t : -1e30f;
                Ps[pbase + (quad * 4 + r) * 72 + nt * 16 + c16] = (f16)__expf(t);
            }
        }

        // ---- P frags; l via MFMA vs ones; O += P V ----
        const int prow = pbase + c16 * 72;
        half8 pa0 = *(const half8*)&Ps[prow + quad * 8];
        half8 pa1 = *(const half8*)&Ps[prow + 32 + quad * 8];
        lacc = __builtin_amdgcn_mfma_f32_16x16x32_f16(pa0, ones, lacc, 0, 0, 0);
        lacc = __builtin_amdgcn_mfma_f32_16x16x32_f16(pa1, ones, lacc, 0, 0, 0);
        #pragma unroll
        for (int dt = 0; dt < 4; ++dt) {
            const int vrow = (dt * 16 + c16) * 72;
            half8 vh0 = *(const half8*)&Vs[vrow + quad * 8];
            half8 vh1 = *(const half8*)&Vs[vrow + 32 + quad * 8];
            O[dt] = __builtin_amdgcn_mfma_f32_16x16x32_f16(pa0, vh0, O[dt], 0, 0, 0);
            O[dt] = __builtin_amdgcn_mfma_f32_16x16x32_f16(pa1, vh1, O[dt], 0, 0, 0);
        }
    }

    // epilogue: normalize, store fp32
    #pragma unroll
    for (int r = 0; r < 4; ++r) {
        float inv = 1.0f / lacc[r];
        size_t orow = (size_t)(b * SEQ + q0 + quad * 4 + r) * HDIM;
        #pragma unroll
        for (int dt = 0; dt < 4; ++dt)
            out[orow + dt * 16 + c16] = O[dt][r] * inv;
    }
}

// ---------------------------------------------------------------------------
extern "C" void kernel_launch(void* const* d_in, const int* in_sizes, int n_in,
                              void* d_out, int out_size, void* d_ws, size_t ws_size,
                              hipStream_t stream) {
    const float* x    = (const float*)d_in[0];
    const int*   mask = (const int*)  d_in[1];
    const float* Wq   = (const float*)d_in[2];
    const float* bq   = (const float*)d_in[3];
    const float* Wk   = (const float*)d_in[4];
    const float* bk   = (const float*)d_in[5];
    const float* Wv   = (const float*)d_in[6];
    const float* bv   = (const float*)d_in[7];
    float* out = (float*)d_out;

    // workspace: Qf, Kf, Vt (fp16, 4 MB each) + Wt (384 KB) = 12.4 MB
    f16* Qf = (f16*)d_ws;
    f16* Kf = Qf + (size_t)NE;
    f16* Vt = Kf + (size_t)NE;
    f16* Wt = Vt + (size_t)NE;

    wprep_kernel<<<dim3(768), dim3(256), 0, stream>>>(Wq, Wk, Wv, Wt);

    qkv_mfma_kernel<<<dim3(MTOT / 64), dim3(256), 0, stream>>>(
        x, Wt, bq, bk, bv, Qf, Kf, Vt);

    attn_mfma_kernel<<<dim3(SEQ / 64, BATCH), dim3(256), 0, stream>>>(
        Qf, Kf, Vt, mask, out);
}